// Round 2
// baseline (1724.142 us; speedup 1.0000x reference)
//
#include <hip/hip_runtime.h>

#define IN_DIM 128
#define H1 32
#define H2 16

// ================= common =================

// degree count (col side; self-loop added as +1 later)
__global__ void k_count(const int* __restrict__ col, int* __restrict__ deg, int E) {
    int e = blockIdx.x * blockDim.x + threadIdx.x;
    if (e < E) atomicAdd(&deg[col[e]], 1);
}

// dense projection: hout[N][OD] = xin[N][KD] @ W[KD][OD]
template <int KD, int OD>
__global__ void k_mm(const float* __restrict__ xin, const float* __restrict__ W,
                     float* __restrict__ hout, int N) {
    __shared__ float Ws[KD * OD];
    for (int t = threadIdx.x; t < KD * OD; t += blockDim.x) Ws[t] = W[t];
    __syncthreads();
    int idx = blockIdx.x * blockDim.x + threadIdx.x;
    int i = idx / OD, d = idx % OD;
    if (i >= N) return;
    const float* xr = xin + (long)i * KD;
    float acc = 0.f;
#pragma unroll
    for (int k = 0; k < KD; ++k) acc = fmaf(xr[k], Ws[k * OD + d], acc);
    hout[idx] = acc;
}

// ================= CSR path =================

// block-wide scan: row_ptr (exclusive), cursor copy, dinv = rsqrt(deg+1)
#define SCAN_T 1024
__global__ void k_scan(const int* __restrict__ deg, int* __restrict__ row_ptr,
                       int* __restrict__ cursor, float* __restrict__ dinv, int N) {
    __shared__ int sums[SCAN_T];
    int t = threadIdx.x;
    int per = (N + SCAN_T - 1) / SCAN_T;   // 10 for N=10000
    int start = t * per;
    int local[16];
    int s = 0;
    for (int k = 0; k < per && k < 16; ++k) {
        int i = start + k;
        int v = (i < N) ? deg[i] : 0;
        local[k] = s;
        s += v;
    }
    sums[t] = s;
    __syncthreads();
    for (int off = 1; off < SCAN_T; off <<= 1) {
        int v = (t >= off) ? sums[t - off] : 0;
        __syncthreads();
        sums[t] += v;
        __syncthreads();
    }
    int base = (t > 0) ? sums[t - 1] : 0;
    for (int k = 0; k < per && k < 16; ++k) {
        int i = start + k;
        if (i < N) {
            int rp = base + local[k];
            row_ptr[i] = rp;
            cursor[i] = rp;
            dinv[i] = rsqrtf((float)deg[i] + 1.0f);
        }
    }
    if (t == SCAN_T - 1) row_ptr[N] = sums[t];
}

// fill CSR: group source nodes by destination
__global__ void k_fill(const int* __restrict__ row, const int* __restrict__ col,
                       int* __restrict__ cursor, int* __restrict__ csr_src, int E) {
    int e = blockIdx.x * blockDim.x + threadIdx.x;
    if (e < E) {
        int c = col[e];
        int pos = atomicAdd(&cursor[c], 1);
        csr_src[pos] = row[e];
    }
}

// gather: out[c] = (sum_{r in in(c)} h[r]*dinv[r])*dinv[c] + h[c]*dinv[c]^2 + b
// one wave per node; 64 lanes = (64/D) edge-parallel groups x D dims
template <int D, bool RELU>
__global__ void k_gather(const int* __restrict__ row_ptr, const int* __restrict__ csr_src,
                         const float* __restrict__ dinv, const float* __restrict__ h,
                         const float* __restrict__ bias, float* __restrict__ out, int N) {
    constexpr int SUB = 64 / D;
    int c = blockIdx.x * (blockDim.x >> 6) + (threadIdx.x >> 6);
    if (c >= N) return;
    int lane = threadIdx.x & 63;
    int sub = lane / D, d = lane % D;
    int beg = row_ptr[c], end = row_ptr[c + 1];
    float acc = 0.f;
    for (int k = beg + sub; k < end; k += SUB) {
        int src = csr_src[k];
        acc += h[(long)src * D + d] * dinv[src];
    }
#pragma unroll
    for (int off = D; off < 64; off <<= 1)
        acc += __shfl_xor(acc, off, 64);
    if (lane < D) {
        float di = dinv[c];
        float v = acc * di + h[(long)c * D + d] * di * di + bias[d];
        out[(long)c * D + d] = RELU ? fmaxf(v, 0.f) : v;
    }
}

// ================= fallback (atomic scatter) path =================

__global__ void k_dinv_i(const int* __restrict__ deg, float* __restrict__ dinv, int N) {
    int i = blockIdx.x * blockDim.x + threadIdx.x;
    if (i < N) dinv[i] = rsqrtf((float)deg[i] + 1.0f);
}

template <int D>
__global__ void k_scatter(const int* __restrict__ row, const int* __restrict__ col,
                          const float* __restrict__ dinv, const float* __restrict__ hin,
                          float* __restrict__ agg, int E) {
    int idx = blockIdx.x * blockDim.x + threadIdx.x;
    int e = idx / D, d = idx % D;
    if (e >= E) return;
    int r = row[e], c = col[e];
    float nrm = dinv[r] * dinv[c];
    atomicAdd(&agg[(long)c * D + d], hin[(long)r * D + d] * nrm);
}

template <int D, bool RELU>
__global__ void k_finish(const float* __restrict__ hproj, const float* __restrict__ dinv,
                         const float* __restrict__ bias, float* __restrict__ agg, int N) {
    int idx = blockIdx.x * blockDim.x + threadIdx.x;
    if (idx >= N * D) return;
    int i = idx / D, d = idx % D;
    float di = dinv[i];
    float v = agg[idx] + hproj[idx] * di * di + bias[d];
    agg[idx] = RELU ? fmaxf(v, 0.f) : v;
}

// ================= decode: out[i][j] = dot(z[i], z[j]) =================
// 64x64 tile, 256 threads, 4x4 register tile, k-major transposed LDS (stride 64
// floats -> per-lane stride 4 -> 2-way bank access = free)
#define DTILE 64
#define KS 16

__global__ void k_decode(const float* __restrict__ z, float* __restrict__ out, int N) {
    __shared__ float ziT[KS * DTILE];
    __shared__ float zjT[KS * DTILE];
    int bi = blockIdx.y * DTILE, bj = blockIdx.x * DTILE;
    int t = threadIdx.x;
    {
        int rr = t >> 2, cc = (t & 3) * 4;   // 64 rows x 4 float4-chunks
        int gi = bi + rr, gj = bj + rr;
        float4 vi = make_float4(0.f, 0.f, 0.f, 0.f), vj = vi;
        if (gi < N) vi = *reinterpret_cast<const float4*>(&z[(long)gi * KS + cc]);
        if (gj < N) vj = *reinterpret_cast<const float4*>(&z[(long)gj * KS + cc]);
        float vis[4] = {vi.x, vi.y, vi.z, vi.w};
        float vjs[4] = {vj.x, vj.y, vj.z, vj.w};
#pragma unroll
        for (int w = 0; w < 4; ++w) {
            ziT[(cc + w) * DTILE + rr] = vis[w];
            zjT[(cc + w) * DTILE + rr] = vjs[w];
        }
    }
    __syncthreads();
    int tx = t & 15, ty = t >> 4;
    float acc[4][4] = {};
#pragma unroll
    for (int k = 0; k < KS; ++k) {
        float4 a = *reinterpret_cast<const float4*>(&ziT[k * DTILE + ty * 4]);
        float4 b = *reinterpret_cast<const float4*>(&zjT[k * DTILE + tx * 4]);
        float as[4] = {a.x, a.y, a.z, a.w};
        float bs[4] = {b.x, b.y, b.z, b.w};
#pragma unroll
        for (int u = 0; u < 4; ++u)
#pragma unroll
            for (int v = 0; v < 4; ++v)
                acc[u][v] = fmaf(as[u], bs[v], acc[u][v]);
    }
#pragma unroll
    for (int u = 0; u < 4; ++u) {
        int gi = bi + ty * 4 + u;
        if (gi >= N) continue;
        int gj = bj + tx * 4;
        long base = (long)gi * N + gj;
        if (gj + 3 < N) {
            *reinterpret_cast<float4*>(&out[base]) =
                make_float4(acc[u][0], acc[u][1], acc[u][2], acc[u][3]);
        } else {
            for (int v2 = 0; v2 < 4; ++v2)
                if (gj + v2 < N) out[base + v2] = acc[u][v2];
        }
    }
}

// ================= launch =================

extern "C" void kernel_launch(void* const* d_in, const int* in_sizes, int n_in,
                              void* d_out, int out_size, void* d_ws, size_t ws_size,
                              hipStream_t stream) {
    const float* x  = (const float*)d_in[0];
    const int*   ei = (const int*)d_in[1];
    const float* W1 = (const float*)d_in[2];
    const float* b1 = (const float*)d_in[3];
    const float* W2 = (const float*)d_in[4];
    const float* b2 = (const float*)d_in[5];
    float* out = (float*)d_out;

    const int N = in_sizes[0] / IN_DIM;   // 10000
    const int E = in_sizes[1] / 2;        // 640000
    const int* row = ei;
    const int* col = ei + E;

    // padded element counts (keep every region 16B-aligned)
    const long N4  = (N + 3) & ~3L;          // 10000
    const long RP4 = (N + 8) & ~3L;          // row_ptr: N+1 rounded up
    const long csr_elems = (E + 3) & ~3L;

    const long need = N4 /*deg*/ + RP4 /*row_ptr*/ + N4 /*cursor*/ + csr_elems
                    + N4 /*dinv*/ + 2L * N * H1 + 2L * N * H2;

    if (ws_size >= (size_t)need * 4) {
        // ---- CSR gather path ----
        int*   deg     = (int*)d_ws;
        int*   row_ptr = deg + N4;
        int*   cursor  = row_ptr + RP4;
        int*   csr_src = cursor + N4;
        float* dinv    = (float*)(csr_src + csr_elems);
        float* h       = dinv + N4;          // x@W1
        float* h1      = h + (long)N * H1;   // layer-1 output (relu)
        float* h2      = h1 + (long)N * H1;  // h1@W2
        float* zz      = h2 + (long)N * H2;  // layer-2 output (z)

        hipMemsetAsync(deg, 0, (size_t)N * sizeof(int), stream);
        k_count<<<(E + 255) / 256, 256, 0, stream>>>(col, deg, E);
        k_scan<<<1, SCAN_T, 0, stream>>>(deg, row_ptr, cursor, dinv, N);
        k_fill<<<(E + 255) / 256, 256, 0, stream>>>(row, col, cursor, csr_src, E);

        k_mm<IN_DIM, H1><<<((long)N * H1 + 255) / 256, 256, 0, stream>>>(x, W1, h, N);
        k_gather<H1, true><<<(N + 3) / 4, 256, 0, stream>>>(row_ptr, csr_src, dinv, h, b1, h1, N);

        k_mm<H1, H2><<<((long)N * H2 + 255) / 256, 256, 0, stream>>>(h1, W2, h2, N);
        k_gather<H2, false><<<(N + 3) / 4, 256, 0, stream>>>(row_ptr, csr_src, dinv, h2, b2, zz, N);

        dim3 dgrid((N + DTILE - 1) / DTILE, (N + DTILE - 1) / DTILE);
        k_decode<<<dgrid, 256, 0, stream>>>(zz, out, N);
    } else {
        // ---- fallback: atomic scatter path (R0-proven) ----
        int*   deg  = (int*)d_ws;
        float* dinv = (float*)(deg + N4);
        float* h    = dinv + N4;
        float* h1   = h + (long)N * H1;
        float* h2   = h1 + (long)N * H1;
        float* zz   = h2 + (long)N * H2;

        hipMemsetAsync(deg, 0, (size_t)N * sizeof(int), stream);
        hipMemsetAsync(h1, 0, (size_t)N * H1 * sizeof(float), stream);
        hipMemsetAsync(zz, 0, (size_t)N * H2 * sizeof(float), stream);

        k_count<<<(E + 255) / 256, 256, 0, stream>>>(col, deg, E);
        k_dinv_i<<<(N + 255) / 256, 256, 0, stream>>>(deg, dinv, N);

        k_mm<IN_DIM, H1><<<((long)N * H1 + 255) / 256, 256, 0, stream>>>(x, W1, h, N);
        k_scatter<H1><<<((long)E * H1 + 255) / 256, 256, 0, stream>>>(row, col, dinv, h, h1, E);
        k_finish<H1, true><<<((long)N * H1 + 255) / 256, 256, 0, stream>>>(h, dinv, b1, h1, N);

        k_mm<H1, H2><<<((long)N * H2 + 255) / 256, 256, 0, stream>>>(h1, W2, h2, N);
        k_scatter<H2><<<((long)E * H2 + 255) / 256, 256, 0, stream>>>(row, col, dinv, h2, zz, E);
        k_finish<H2, false><<<((long)N * H2 + 255) / 256, 256, 0, stream>>>(h2, dinv, b2, zz, N);

        dim3 dgrid((N + DTILE - 1) / DTILE, (N + DTILE - 1) / DTILE);
        k_decode<<<dgrid, 256, 0, stream>>>(zz, out, N);
    }
}

// Round 3
// 365.342 us; speedup vs baseline: 4.7193x; 4.7193x over previous
//
#include <hip/hip_runtime.h>

#define IN_DIM 128
#define H1 32
#define H2 16

// ---------------- degree count (col side, self-loop added in k_dinv) ----------
__global__ void k_count(const int* __restrict__ col, float* __restrict__ deg, int E) {
    int e = blockIdx.x * blockDim.x + threadIdx.x;
    if (e < E) atomicAdd(&deg[col[e]], 1.0f);
}

__global__ void k_dinv(float* __restrict__ deg, int N) {
    int i = blockIdx.x * blockDim.x + threadIdx.x;
    if (i < N) deg[i] = rsqrtf(deg[i] + 1.0f);   // +1 = self loop; deg>0 always
}

// ---------------- dense projection: hout[N][OD] = xin[N][KD] @ W[KD][OD] ------
template <int KD, int OD>
__global__ void k_mm(const float* __restrict__ xin, const float* __restrict__ W,
                     float* __restrict__ hout, int N) {
    __shared__ float Ws[KD * OD];
    for (int t = threadIdx.x; t < KD * OD; t += blockDim.x) Ws[t] = W[t];
    __syncthreads();
    int idx = blockIdx.x * blockDim.x + threadIdx.x;
    int i = idx / OD, d = idx % OD;
    if (i >= N) return;
    const float* xr = xin + (long)i * KD;
    float acc = 0.f;
#pragma unroll
    for (int k = 0; k < KD; ++k) acc = fmaf(xr[k], Ws[k * OD + d], acc);
    hout[idx] = acc;
}

// ---------------- edge scatter: agg[c][d] += hin[r][d] * dinv[r]*dinv[c] ------
template <int D>
__global__ void k_scatter(const int* __restrict__ row, const int* __restrict__ col,
                          const float* __restrict__ dinv, const float* __restrict__ hin,
                          float* __restrict__ agg, int E) {
    int idx = blockIdx.x * blockDim.x + threadIdx.x;
    int e = idx / D, d = idx % D;   // consecutive lanes share e -> broadcast idx loads, coalesced h
    if (e >= E) return;
    int r = row[e], c = col[e];
    float nrm = dinv[r] * dinv[c];
    atomicAdd(&agg[(long)c * D + d], hin[(long)r * D + d] * nrm);
}

// ---------------- self-loop + bias (+relu): agg = act(agg + h*dinv^2 + b) -----
template <int D, bool RELU>
__global__ void k_finish(const float* __restrict__ hproj, const float* __restrict__ dinv,
                         const float* __restrict__ bias, float* __restrict__ agg, int N) {
    int idx = blockIdx.x * blockDim.x + threadIdx.x;
    if (idx >= N * D) return;
    int i = idx / D, d = idx % D;
    float di = dinv[i];
    float v = agg[idx] + hproj[idx] * di * di + bias[d];
    agg[idx] = RELU ? fmaxf(v, 0.f) : v;
}

// ---------------- decode: out[i][j] = dot(z[i], z[j]), 64x64 tile / 4x4 thread
#define DTILE 64
#define DPAD 20   // padded row stride in floats; 80B keeps float4 alignment, breaks bank aliasing

__global__ void k_decode(const float* __restrict__ z, float* __restrict__ out, int N) {
    __shared__ float zi[DTILE * DPAD];
    __shared__ float zj[DTILE * DPAD];
    int bi = blockIdx.y * DTILE, bj = blockIdx.x * DTILE;
    int t = threadIdx.x;
    {
        int rr = t >> 2, cc = (t & 3) * 4;   // 256 threads: one float4 each per tile
        int gi = bi + rr, gj = bj + rr;
        float4 vi = make_float4(0.f, 0.f, 0.f, 0.f), vj = vi;
        if (gi < N) vi = *reinterpret_cast<const float4*>(&z[(long)gi * H2 + cc]);
        if (gj < N) vj = *reinterpret_cast<const float4*>(&z[(long)gj * H2 + cc]);
        *reinterpret_cast<float4*>(&zi[rr * DPAD + cc]) = vi;
        *reinterpret_cast<float4*>(&zj[rr * DPAD + cc]) = vj;
    }
    __syncthreads();
    int tx = t & 15, ty = t >> 4;
    float acc[4][4] = {};
#pragma unroll
    for (int kc = 0; kc < 4; ++kc) {
        float4 a[4], b[4];
#pragma unroll
        for (int u = 0; u < 4; ++u)
            a[u] = *reinterpret_cast<const float4*>(&zi[(ty * 4 + u) * DPAD + kc * 4]);
#pragma unroll
        for (int v = 0; v < 4; ++v)
            b[v] = *reinterpret_cast<const float4*>(&zj[(tx * 4 + v) * DPAD + kc * 4]);
#pragma unroll
        for (int u = 0; u < 4; ++u)
#pragma unroll
            for (int v = 0; v < 4; ++v)
                acc[u][v] += a[u].x * b[v].x + a[u].y * b[v].y +
                             a[u].z * b[v].z + a[u].w * b[v].w;
    }
#pragma unroll
    for (int u = 0; u < 4; ++u) {
        int gi = bi + ty * 4 + u;
        if (gi >= N) continue;
        int gj = bj + tx * 4;
        long base = (long)gi * N + gj;
        if (gj + 3 < N) {
            *reinterpret_cast<float4*>(&out[base]) =
                make_float4(acc[u][0], acc[u][1], acc[u][2], acc[u][3]);
        } else {
            for (int v2 = 0; v2 < 4; ++v2)
                if (gj + v2 < N) out[base + v2] = acc[u][v2];
        }
    }
}

extern "C" void kernel_launch(void* const* d_in, const int* in_sizes, int n_in,
                              void* d_out, int out_size, void* d_ws, size_t ws_size,
                              hipStream_t stream) {
    const float* x  = (const float*)d_in[0];
    const int*   ei = (const int*)d_in[1];
    const float* W1 = (const float*)d_in[2];
    const float* b1 = (const float*)d_in[3];
    const float* W2 = (const float*)d_in[4];
    const float* b2 = (const float*)d_in[5];
    float* out = (float*)d_out;

    const int N = in_sizes[0] / IN_DIM;   // 10000
    const int E = in_sizes[1] / 2;        // 640000
    const int* row = ei;
    const int* col = ei + E;

    // workspace layout (all offsets 64B-aligned for N=10000)
    float* w    = (float*)d_ws;
    float* dinv = w;                       // N
    float* h    = dinv + N;                // N*H1  (x@W1)
    float* h1   = h + (long)N * H1;        // N*H1  (agg1 -> relu'd hidden)
    float* h2   = h1 + (long)N * H1;       // N*H2  (h1@W2)
    float* zz   = h2 + (long)N * H2;       // N*H2  (agg2 -> z), byte off 3,240,000 (64B-aligned)

    hipMemsetAsync(dinv, 0, (size_t)N * sizeof(float), stream);
    hipMemsetAsync(h1,   0, (size_t)N * H1 * sizeof(float), stream);
    hipMemsetAsync(zz,   0, (size_t)N * H2 * sizeof(float), stream);

    k_count<<<(E + 255) / 256, 256, 0, stream>>>(col, dinv, E);
    k_dinv<<<(N + 255) / 256, 256, 0, stream>>>(dinv, N);

    k_mm<IN_DIM, H1><<<((long)N * H1 + 255) / 256, 256, 0, stream>>>(x, W1, h, N);
    k_scatter<H1><<<((long)E * H1 + 255) / 256, 256, 0, stream>>>(row, col, dinv, h, h1, E);
    k_finish<H1, true><<<((long)N * H1 + 255) / 256, 256, 0, stream>>>(h, dinv, b1, h1, N);

    k_mm<H1, H2><<<((long)N * H2 + 255) / 256, 256, 0, stream>>>(h1, W2, h2, N);
    k_scatter<H2><<<((long)E * H2 + 255) / 256, 256, 0, stream>>>(row, col, dinv, h2, zz, E);
    k_finish<H2, false><<<((long)N * H2 + 255) / 256, 256, 0, stream>>>(h2, dinv, b2, zz, N);

    dim3 dgrid((N + DTILE - 1) / DTILE, (N + DTILE - 1) / DTILE);
    k_decode<<<dgrid, 256, 0, stream>>>(zz, out, N);
}

// Round 4
// 294.817 us; speedup vs baseline: 5.8482x; 1.2392x over previous
//
#include <hip/hip_runtime.h>

#define IN_DIM 128
#define H1 32
#define H2 16

// ---------------- degree count (col side, self-loop added in k_dinv) ----------
__global__ void k_count(const int* __restrict__ col, float* __restrict__ deg, int E) {
    int e = blockIdx.x * blockDim.x + threadIdx.x;
    if (e < E) atomicAdd(&deg[col[e]], 1.0f);
}

__global__ void k_dinv(float* __restrict__ deg, int N) {
    int i = blockIdx.x * blockDim.x + threadIdx.x;
    if (i < N) deg[i] = rsqrtf(deg[i] + 1.0f);   // +1 = self loop; deg>0 always
}

// ---------------- dense projection: hout[N][OD] = xin[N][KD] @ W[KD][OD] ------
template <int KD, int OD>
__global__ void k_mm(const float* __restrict__ xin, const float* __restrict__ W,
                     float* __restrict__ hout, int N) {
    __shared__ float Ws[KD * OD];
    for (int t = threadIdx.x; t < KD * OD; t += blockDim.x) Ws[t] = W[t];
    __syncthreads();
    int idx = blockIdx.x * blockDim.x + threadIdx.x;
    int i = idx / OD, d = idx % OD;
    if (i >= N) return;
    const float* xr = xin + (long)i * KD;
    float acc = 0.f;
#pragma unroll
    for (int k = 0; k < KD; ++k) acc = fmaf(xr[k], Ws[k * OD + d], acc);
    hout[idx] = acc;
}

// ---------------- edge scatter: agg[c][d] += hin[r][d] * dinv[r]*dinv[c] ------
template <int D>
__global__ void k_scatter(const int* __restrict__ row, const int* __restrict__ col,
                          const float* __restrict__ dinv, const float* __restrict__ hin,
                          float* __restrict__ agg, int E) {
    int idx = blockIdx.x * blockDim.x + threadIdx.x;
    int e = idx / D, d = idx % D;   // consecutive lanes share e -> broadcast idx loads, coalesced h
    if (e >= E) return;
    int r = row[e], c = col[e];
    float nrm = dinv[r] * dinv[c];
    atomicAdd(&agg[(long)c * D + d], hin[(long)r * D + d] * nrm);
}

// ---------------- self-loop + bias (+relu): agg = act(agg + h*dinv^2 + b) -----
template <int D, bool RELU>
__global__ void k_finish(const float* __restrict__ hproj, const float* __restrict__ dinv,
                         const float* __restrict__ bias, float* __restrict__ agg, int N) {
    int idx = blockIdx.x * blockDim.x + threadIdx.x;
    if (idx >= N * D) return;
    int i = idx / D, d = idx % D;
    float di = dinv[i];
    float v = agg[idx] + hproj[idx] * di * di + bias[d];
    agg[idx] = RELU ? fmaxf(v, 0.f) : v;
}

// ---------------- decode: out[i][j] = dot(z[i], z[j]) ------------------------
// 128x128 block tile, 256 threads, 8x8 register tile.
// LDS layout is k-major [k][row]: per-k each thread reads 8 contiguous floats
// (2x ds_read_b128); a-reads broadcast across 16 lanes (free), b-reads 4-way.
// 16 FMA per ds_read_b128 (2x the 4x4 version) -> LDS pipe drops below the
// 400MB d_out write floor (~58us @ 6.9TB/s measured fill BW).
#define DT 128

__global__ void k_decode(const float* __restrict__ z, float* __restrict__ out, int N) {
    __shared__ float ziT[16][DT];
    __shared__ float zjT[16][DT];
    int bi = blockIdx.y * DT, bj = blockIdx.x * DT;
    int t = threadIdx.x;

    // staging: threads 0..127 load zi rows, 128..255 load zj rows (64B/row, coalesced)
    {
        int r = t & 127;
        int gi = (t < 128 ? bi : bj) + r;
        float4 v0 = make_float4(0.f, 0.f, 0.f, 0.f), v1 = v0, v2 = v0, v3 = v0;
        if (gi < N) {
            const float4* zp = reinterpret_cast<const float4*>(z + (long)gi * 16);
            v0 = zp[0]; v1 = zp[1]; v2 = zp[2]; v3 = zp[3];
        }
        float vals[16] = {v0.x, v0.y, v0.z, v0.w, v1.x, v1.y, v1.z, v1.w,
                          v2.x, v2.y, v2.z, v2.w, v3.x, v3.y, v3.z, v3.w};
        float (*dst)[DT] = (t < 128) ? ziT : zjT;
#pragma unroll
        for (int k = 0; k < 16; ++k) dst[k][r] = vals[k];   // stride-1 lanes: conflict-free
    }
    __syncthreads();

    int tx = t & 15, ty = t >> 4;
    float acc[8][8] = {};
#pragma unroll 4
    for (int k = 0; k < 16; ++k) {
        float a[8], b[8];
        float4 a0 = *reinterpret_cast<const float4*>(&ziT[k][ty * 8]);
        float4 a1 = *reinterpret_cast<const float4*>(&ziT[k][ty * 8 + 4]);
        float4 b0 = *reinterpret_cast<const float4*>(&zjT[k][tx * 8]);
        float4 b1 = *reinterpret_cast<const float4*>(&zjT[k][tx * 8 + 4]);
        a[0]=a0.x; a[1]=a0.y; a[2]=a0.z; a[3]=a0.w; a[4]=a1.x; a[5]=a1.y; a[6]=a1.z; a[7]=a1.w;
        b[0]=b0.x; b[1]=b0.y; b[2]=b0.z; b[3]=b0.w; b[4]=b1.x; b[5]=b1.y; b[6]=b1.z; b[7]=b1.w;
#pragma unroll
        for (int u = 0; u < 8; ++u)
#pragma unroll
            for (int v = 0; v < 8; ++v)
                acc[u][v] = fmaf(a[u], b[v], acc[u][v]);
    }

#pragma unroll
    for (int u = 0; u < 8; ++u) {
        int gi = bi + ty * 8 + u;
        if (gi >= N) continue;
        int gj = bj + tx * 8;
        long base = (long)gi * N + gj;
        if (gj + 7 < N) {
            *reinterpret_cast<float4*>(&out[base]) =
                make_float4(acc[u][0], acc[u][1], acc[u][2], acc[u][3]);
            *reinterpret_cast<float4*>(&out[base + 4]) =
                make_float4(acc[u][4], acc[u][5], acc[u][6], acc[u][7]);
        } else {
            for (int v2 = 0; v2 < 8; ++v2)
                if (gj + v2 < N) out[base + v2] = acc[u][v2];
        }
    }
}

extern "C" void kernel_launch(void* const* d_in, const int* in_sizes, int n_in,
                              void* d_out, int out_size, void* d_ws, size_t ws_size,
                              hipStream_t stream) {
    const float* x  = (const float*)d_in[0];
    const int*   ei = (const int*)d_in[1];
    const float* W1 = (const float*)d_in[2];
    const float* b1 = (const float*)d_in[3];
    const float* W2 = (const float*)d_in[4];
    const float* b2 = (const float*)d_in[5];
    float* out = (float*)d_out;

    const int N = in_sizes[0] / IN_DIM;   // 10000
    const int E = in_sizes[1] / 2;        // 640000
    const int* row = ei;
    const int* col = ei + E;

    // workspace layout (all offsets 64B-aligned for N=10000)
    float* w    = (float*)d_ws;
    float* dinv = w;                       // N
    float* h    = dinv + N;                // N*H1  (x@W1)
    float* h1   = h + (long)N * H1;        // N*H1  (agg1 -> relu'd hidden)
    float* h2   = h1 + (long)N * H1;       // N*H2  (h1@W2)
    float* zz   = h2 + (long)N * H2;       // N*H2  (agg2 -> z), byte off 3,240,000 (64B-aligned)

    hipMemsetAsync(dinv, 0, (size_t)N * sizeof(float), stream);
    hipMemsetAsync(h1,   0, (size_t)N * H1 * sizeof(float), stream);
    hipMemsetAsync(zz,   0, (size_t)N * H2 * sizeof(float), stream);

    k_count<<<(E + 255) / 256, 256, 0, stream>>>(col, dinv, E);
    k_dinv<<<(N + 255) / 256, 256, 0, stream>>>(dinv, N);

    k_mm<IN_DIM, H1><<<((long)N * H1 + 255) / 256, 256, 0, stream>>>(x, W1, h, N);
    k_scatter<H1><<<((long)E * H1 + 255) / 256, 256, 0, stream>>>(row, col, dinv, h, h1, E);
    k_finish<H1, true><<<((long)N * H1 + 255) / 256, 256, 0, stream>>>(h, dinv, b1, h1, N);

    k_mm<H1, H2><<<((long)N * H2 + 255) / 256, 256, 0, stream>>>(h1, W2, h2, N);
    k_scatter<H2><<<((long)E * H2 + 255) / 256, 256, 0, stream>>>(row, col, dinv, h2, zz, E);
    k_finish<H2, false><<<((long)N * H2 + 255) / 256, 256, 0, stream>>>(h2, dinv, b2, zz, N);

    dim3 dgrid((N + DT - 1) / DT, (N + DT - 1) / DT);
    k_decode<<<dgrid, 256, 0, stream>>>(zz, out, N);
}

// Round 5
// 266.982 us; speedup vs baseline: 6.4579x; 1.1043x over previous
//
#include <hip/hip_runtime.h>

#define IN_DIM 128
#define H1 32
#define H2 16

// ================= CSR build =================

__global__ void k_count(const int* __restrict__ col, int* __restrict__ deg, int E) {
    int e = blockIdx.x * blockDim.x + threadIdx.x;
    if (e < E) atomicAdd(&deg[col[e]], 1);
}

// single-block scan: row_ptr (exclusive), cursor copy, dinv = rsqrt(deg+1)
#define SCAN_T 1024
__global__ void k_scan(const int* __restrict__ deg, int* __restrict__ row_ptr,
                       int* __restrict__ cursor, float* __restrict__ dinv, int N) {
    __shared__ int sums[SCAN_T];
    int t = threadIdx.x;
    int per = (N + SCAN_T - 1) / SCAN_T;   // 10 for N=10000
    int start = t * per;
    int local[16];
    int s = 0;
    for (int k = 0; k < per && k < 16; ++k) {
        int i = start + k;
        int v = (i < N) ? deg[i] : 0;
        local[k] = s;
        s += v;
    }
    sums[t] = s;
    __syncthreads();
    for (int off = 1; off < SCAN_T; off <<= 1) {
        int v = (t >= off) ? sums[t - off] : 0;
        __syncthreads();
        sums[t] += v;
        __syncthreads();
    }
    int base = (t > 0) ? sums[t - 1] : 0;
    for (int k = 0; k < per && k < 16; ++k) {
        int i = start + k;
        if (i < N) {
            int rp = base + local[k];
            row_ptr[i] = rp;
            cursor[i] = rp;
            dinv[i] = rsqrtf((float)deg[i] + 1.0f);
        }
    }
    if (t == SCAN_T - 1) row_ptr[N] = sums[t];
}

__global__ void k_fill(const int* __restrict__ row, const int* __restrict__ col,
                       int* __restrict__ cursor, int* __restrict__ csr_src, int E) {
    int e = blockIdx.x * blockDim.x + threadIdx.x;
    if (e < E) {
        int c = col[e];
        int pos = atomicAdd(&cursor[c], 1);
        csr_src[pos] = row[e];
    }
}

// ================= dense projection =================

template <int KD, int OD>
__global__ void k_mm(const float* __restrict__ xin, const float* __restrict__ W,
                     float* __restrict__ hout, int N) {
    __shared__ float Ws[KD * OD];
    for (int t = threadIdx.x; t < KD * OD; t += blockDim.x) Ws[t] = W[t];
    __syncthreads();
    int idx = blockIdx.x * blockDim.x + threadIdx.x;
    int i = idx / OD, d = idx % OD;
    if (i >= N) return;
    const float* xr = xin + (long)i * KD;
    float acc = 0.f;
#pragma unroll
    for (int k = 0; k < KD; ++k) acc = fmaf(xr[k], Ws[k * OD + d], acc);
    hout[idx] = acc;
}

// ================= CSR gather (fused norm + self-loop + bias + act) ==========
// out[c] = (sum_{r in in(c)} h[r]*dinv[r])*dinv[c] + h[c]*dinv[c]^2 + b
// one wave per node; 64 lanes = (64/D) edge-parallel groups x D dims
template <int D, bool RELU>
__global__ void k_gather(const int* __restrict__ row_ptr, const int* __restrict__ csr_src,
                         const float* __restrict__ dinv, const float* __restrict__ h,
                         const float* __restrict__ bias, float* __restrict__ out, int N) {
    constexpr int SUB = 64 / D;
    int c = blockIdx.x * (blockDim.x >> 6) + (threadIdx.x >> 6);
    if (c >= N) return;
    int lane = threadIdx.x & 63;
    int sub = lane / D, d = lane % D;
    int beg = row_ptr[c], end = row_ptr[c + 1];
    float acc = 0.f;
    for (int k = beg + sub; k < end; k += SUB) {
        int src = csr_src[k];
        acc += h[(long)src * D + d] * dinv[src];
    }
#pragma unroll
    for (int off = D; off < 64; off <<= 1)
        acc += __shfl_xor(acc, off, 64);
    if (lane < D) {
        float di = dinv[c];
        float v = acc * di + h[(long)c * D + d] * di * di + bias[d];
        out[(long)c * D + d] = RELU ? fmaxf(v, 0.f) : v;
    }
}

// ================= atomic fallback (R3-proven) =================

__global__ void k_dinv_i(const int* __restrict__ deg, float* __restrict__ dinv, int N) {
    int i = blockIdx.x * blockDim.x + threadIdx.x;
    if (i < N) dinv[i] = rsqrtf((float)deg[i] + 1.0f);
}

template <int D>
__global__ void k_scatter(const int* __restrict__ row, const int* __restrict__ col,
                          const float* __restrict__ dinv, const float* __restrict__ hin,
                          float* __restrict__ agg, int E) {
    int idx = blockIdx.x * blockDim.x + threadIdx.x;
    int e = idx / D, d = idx % D;
    if (e >= E) return;
    int r = row[e], c = col[e];
    float nrm = dinv[r] * dinv[c];
    atomicAdd(&agg[(long)c * D + d], hin[(long)r * D + d] * nrm);
}

template <int D, bool RELU>
__global__ void k_finish(const float* __restrict__ hproj, const float* __restrict__ dinv,
                         const float* __restrict__ bias, float* __restrict__ agg, int N) {
    int idx = blockIdx.x * blockDim.x + threadIdx.x;
    if (idx >= N * D) return;
    int i = idx / D, d = idx % D;
    float di = dinv[i];
    float v = agg[idx] + hproj[idx] * di * di + bias[d];
    agg[idx] = RELU ? fmaxf(v, 0.f) : v;
}

// ================= decode (R4, unchanged): out[i][j] = dot(z[i], z[j]) =======
// 128x128 block tile, 256 threads, 8x8 register tile, k-major LDS [k][row].
#define DT 128

__global__ void k_decode(const float* __restrict__ z, float* __restrict__ out, int N) {
    __shared__ float ziT[16][DT];
    __shared__ float zjT[16][DT];
    int bi = blockIdx.y * DT, bj = blockIdx.x * DT;
    int t = threadIdx.x;

    {
        int r = t & 127;
        int gi = (t < 128 ? bi : bj) + r;
        float4 v0 = make_float4(0.f, 0.f, 0.f, 0.f), v1 = v0, v2 = v0, v3 = v0;
        if (gi < N) {
            const float4* zp = reinterpret_cast<const float4*>(z + (long)gi * 16);
            v0 = zp[0]; v1 = zp[1]; v2 = zp[2]; v3 = zp[3];
        }
        float vals[16] = {v0.x, v0.y, v0.z, v0.w, v1.x, v1.y, v1.z, v1.w,
                          v2.x, v2.y, v2.z, v2.w, v3.x, v3.y, v3.z, v3.w};
        float (*dst)[DT] = (t < 128) ? ziT : zjT;
#pragma unroll
        for (int k = 0; k < 16; ++k) dst[k][r] = vals[k];
    }
    __syncthreads();

    int tx = t & 15, ty = t >> 4;
    float acc[8][8] = {};
#pragma unroll 4
    for (int k = 0; k < 16; ++k) {
        float a[8], b[8];
        float4 a0 = *reinterpret_cast<const float4*>(&ziT[k][ty * 8]);
        float4 a1 = *reinterpret_cast<const float4*>(&ziT[k][ty * 8 + 4]);
        float4 b0 = *reinterpret_cast<const float4*>(&zjT[k][tx * 8]);
        float4 b1 = *reinterpret_cast<const float4*>(&zjT[k][tx * 8 + 4]);
        a[0]=a0.x; a[1]=a0.y; a[2]=a0.z; a[3]=a0.w; a[4]=a1.x; a[5]=a1.y; a[6]=a1.z; a[7]=a1.w;
        b[0]=b0.x; b[1]=b0.y; b[2]=b0.z; b[3]=b0.w; b[4]=b1.x; b[5]=b1.y; b[6]=b1.z; b[7]=b1.w;
#pragma unroll
        for (int u = 0; u < 8; ++u)
#pragma unroll
            for (int v = 0; v < 8; ++v)
                acc[u][v] = fmaf(a[u], b[v], acc[u][v]);
    }

#pragma unroll
    for (int u = 0; u < 8; ++u) {
        int gi = bi + ty * 8 + u;
        if (gi >= N) continue;
        int gj = bj + tx * 8;
        long base = (long)gi * N + gj;
        if (gj + 7 < N) {
            *reinterpret_cast<float4*>(&out[base]) =
                make_float4(acc[u][0], acc[u][1], acc[u][2], acc[u][3]);
            *reinterpret_cast<float4*>(&out[base + 4]) =
                make_float4(acc[u][4], acc[u][5], acc[u][6], acc[u][7]);
        } else {
            for (int v2 = 0; v2 < 8; ++v2)
                if (gj + v2 < N) out[base + v2] = acc[u][v2];
        }
    }
}

// ================= launch =================

extern "C" void kernel_launch(void* const* d_in, const int* in_sizes, int n_in,
                              void* d_out, int out_size, void* d_ws, size_t ws_size,
                              hipStream_t stream) {
    const float* x  = (const float*)d_in[0];
    const int*   ei = (const int*)d_in[1];
    const float* W1 = (const float*)d_in[2];
    const float* b1 = (const float*)d_in[3];
    const float* W2 = (const float*)d_in[4];
    const float* b2 = (const float*)d_in[5];
    float* out = (float*)d_out;

    const int N = in_sizes[0] / IN_DIM;   // 10000
    const int E = in_sizes[1] / 2;        // 640000
    const int* row = ei;
    const int* col = ei + E;

    // region sizes in elems, each padded to a multiple of 16 elems (64B)
    const long SZ_DEG = (N + 15) & ~15L;        // 10000
    const long SZ_RP  = (N + 1 + 15) & ~15L;    // 10016
    const long SZ_CUR = SZ_DEG;                 // 10000
    const long SZ_CSR = (E + 15) & ~15L;        // 640000
    const long SZ_DI  = SZ_DEG;                 // 10000
    // cumulative elem offsets: all multiples of 16 -> every pointer 64B-aligned
    const long need = SZ_DEG + SZ_RP + SZ_CUR + SZ_CSR + SZ_DI
                    + 2L * N * H1 + 2L * N * H2;

    if (ws_size >= (size_t)need * 4) {
        // ---- CSR gather path ----
        int*   deg     = (int*)d_ws;
        int*   row_ptr = deg + SZ_DEG;
        int*   cursor  = row_ptr + SZ_RP;
        int*   csr_src = cursor + SZ_CUR;
        float* dinv    = (float*)(csr_src + SZ_CSR);
        float* h       = dinv + SZ_DI;       // x@W1        (N*H1)
        float* h1      = h + (long)N * H1;   // layer-1 out (N*H1)
        float* h2      = h1 + (long)N * H1;  // h1@W2       (N*H2)
        float* zz      = h2 + (long)N * H2;  // z           (N*H2), 64B-aligned

        hipMemsetAsync(deg, 0, (size_t)N * sizeof(int), stream);
        k_count<<<(E + 255) / 256, 256, 0, stream>>>(col, deg, E);
        k_scan<<<1, SCAN_T, 0, stream>>>(deg, row_ptr, cursor, dinv, N);
        k_fill<<<(E + 255) / 256, 256, 0, stream>>>(row, col, cursor, csr_src, E);

        k_mm<IN_DIM, H1><<<((long)N * H1 + 255) / 256, 256, 0, stream>>>(x, W1, h, N);
        k_gather<H1, true><<<(N + 3) / 4, 256, 0, stream>>>(row_ptr, csr_src, dinv, h, b1, h1, N);

        k_mm<H1, H2><<<((long)N * H2 + 255) / 256, 256, 0, stream>>>(h1, W2, h2, N);
        k_gather<H2, false><<<(N + 3) / 4, 256, 0, stream>>>(row_ptr, csr_src, dinv, h2, b2, zz, N);

        dim3 dgrid((N + DT - 1) / DT, (N + DT - 1) / DT);
        k_decode<<<dgrid, 256, 0, stream>>>(zz, out, N);
    } else {
        // ---- fallback: atomic scatter path ----
        int*   deg  = (int*)d_ws;
        float* dinv = (float*)(deg + SZ_DEG);
        float* h    = dinv + SZ_DI;
        float* h1   = h + (long)N * H1;
        float* h2   = h1 + (long)N * H1;
        float* zz   = h2 + (long)N * H2;

        hipMemsetAsync(deg, 0, (size_t)N * sizeof(int), stream);
        hipMemsetAsync(h1, 0, (size_t)N * H1 * sizeof(float), stream);
        hipMemsetAsync(zz, 0, (size_t)N * H2 * sizeof(float), stream);

        k_count<<<(E + 255) / 256, 256, 0, stream>>>(col, deg, E);
        k_dinv_i<<<(N + 255) / 256, 256, 0, stream>>>(deg, dinv, N);

        k_mm<IN_DIM, H1><<<((long)N * H1 + 255) / 256, 256, 0, stream>>>(x, W1, h, N);
        k_scatter<H1><<<((long)E * H1 + 255) / 256, 256, 0, stream>>>(row, col, dinv, h, h1, E);
        k_finish<H1, true><<<((long)N * H1 + 255) / 256, 256, 0, stream>>>(h, dinv, b1, h1, N);

        k_mm<H1, H2><<<((long)N * H2 + 255) / 256, 256, 0, stream>>>(h1, W2, h2, N);
        k_scatter<H2><<<((long)E * H2 + 255) / 256, 256, 0, stream>>>(row, col, dinv, h2, zz, E);
        k_finish<H2, false><<<((long)N * H2 + 255) / 256, 256, 0, stream>>>(h2, dinv, b2, zz, N);

        dim3 dgrid((N + DT - 1) / DT, (N + DT - 1) / DT);
        k_decode<<<dgrid, 256, 0, stream>>>(zz, out, N);
    }
}

// Round 6
// 250.091 us; speedup vs baseline: 6.8941x; 1.0675x over previous
//
#include <hip/hip_runtime.h>

#define IN_DIM 128
#define H1 32
#define H2 16

// ================= CSR build =================

__global__ void k_count(const int* __restrict__ col, int* __restrict__ deg, int E) {
    int e = blockIdx.x * blockDim.x + threadIdx.x;
    if (e < E) atomicAdd(&deg[col[e]], 1);
}

// single-block scan: row_ptr (exclusive), cursor copy, dinv = rsqrt(deg+1)
#define SCAN_T 1024
__global__ void k_scan(const int* __restrict__ deg, int* __restrict__ row_ptr,
                       int* __restrict__ cursor, float* __restrict__ dinv, int N) {
    __shared__ int sums[SCAN_T];
    int t = threadIdx.x;
    int per = (N + SCAN_T - 1) / SCAN_T;   // 10 for N=10000
    int start = t * per;
    int local[16];
    int s = 0;
    for (int k = 0; k < per && k < 16; ++k) {
        int i = start + k;
        int v = (i < N) ? deg[i] : 0;
        local[k] = s;
        s += v;
    }
    sums[t] = s;
    __syncthreads();
    for (int off = 1; off < SCAN_T; off <<= 1) {
        int v = (t >= off) ? sums[t - off] : 0;
        __syncthreads();
        sums[t] += v;
        __syncthreads();
    }
    int base = (t > 0) ? sums[t - 1] : 0;
    for (int k = 0; k < per && k < 16; ++k) {
        int i = start + k;
        if (i < N) {
            int rp = base + local[k];
            row_ptr[i] = rp;
            cursor[i] = rp;
            dinv[i] = rsqrtf((float)deg[i] + 1.0f);
        }
    }
    if (t == SCAN_T - 1) row_ptr[N] = sums[t];
}

__global__ void k_fill(const int* __restrict__ row, const int* __restrict__ col,
                       int* __restrict__ cursor, int* __restrict__ csr_src, int E) {
    int e = blockIdx.x * blockDim.x + threadIdx.x;
    if (e < E) {
        int c = col[e];
        int pos = atomicAdd(&cursor[c], 1);
        csr_src[pos] = row[e];
    }
}

// ================= dense projection (float4 loads; optional *dinv epilogue) ==
// SCALE=true: hout[i][d] = (xin[i] @ W)[d] * dinv[i]   (pre-scaled for gather)
template <int KD, int OD, bool SCALE>
__global__ void k_mm(const float* __restrict__ xin, const float* __restrict__ W,
                     const float* __restrict__ dinv, float* __restrict__ hout, int N) {
    __shared__ float Ws[KD * OD];
    for (int t = threadIdx.x; t < KD * OD; t += blockDim.x) Ws[t] = W[t];
    __syncthreads();
    int idx = blockIdx.x * blockDim.x + threadIdx.x;
    int i = idx / OD, d = idx % OD;
    if (i >= N) return;
    const float4* xr = reinterpret_cast<const float4*>(xin + (long)i * KD);
    float acc = 0.f;
#pragma unroll
    for (int k4 = 0; k4 < KD / 4; ++k4) {
        float4 xv = xr[k4];
        acc = fmaf(xv.x, Ws[(4 * k4 + 0) * OD + d], acc);
        acc = fmaf(xv.y, Ws[(4 * k4 + 1) * OD + d], acc);
        acc = fmaf(xv.z, Ws[(4 * k4 + 2) * OD + d], acc);
        acc = fmaf(xv.w, Ws[(4 * k4 + 3) * OD + d], acc);
    }
    hout[idx] = SCALE ? acc * dinv[i] : acc;
}

// ================= CSR gather over pre-scaled h' =============================
// out[c] = dinv[c] * (sum_{r in in(c)} h'[r][d] + h'[c][d]) + b[d]
// one wave per node; 64 lanes = (64/D) edge-groups x D dims; 4x unrolled MLP
template <int D, bool RELU>
__global__ void k_gather(const int* __restrict__ row_ptr, const int* __restrict__ csr_src,
                         const float* __restrict__ dinv, const float* __restrict__ hp,
                         const float* __restrict__ bias, float* __restrict__ out, int N) {
    constexpr int SUB = 64 / D;
    int c = blockIdx.x * (blockDim.x >> 6) + (threadIdx.x >> 6);
    if (c >= N) return;
    int lane = threadIdx.x & 63;
    int sub = lane / D, d = lane % D;
    int beg = row_ptr[c], end = row_ptr[c + 1];
    float a0 = 0.f, a1 = 0.f, a2 = 0.f, a3 = 0.f;
    int k = beg + sub;
    for (; k + 3 * SUB < end; k += 4 * SUB) {   // 4 independent chases in flight
        int s0 = csr_src[k];
        int s1 = csr_src[k + SUB];
        int s2 = csr_src[k + 2 * SUB];
        int s3 = csr_src[k + 3 * SUB];
        a0 += hp[(long)s0 * D + d];
        a1 += hp[(long)s1 * D + d];
        a2 += hp[(long)s2 * D + d];
        a3 += hp[(long)s3 * D + d];
    }
    for (; k < end; k += SUB) {
        int s = csr_src[k];
        a0 += hp[(long)s * D + d];
    }
    float acc = (a0 + a1) + (a2 + a3);
#pragma unroll
    for (int off = D; off < 64; off <<= 1)
        acc += __shfl_xor(acc, off, 64);
    if (lane < D) {
        float v = fmaf(dinv[c], acc + hp[(long)c * D + d], bias[d]);
        out[(long)c * D + d] = RELU ? fmaxf(v, 0.f) : v;
    }
}

// ================= atomic fallback (R3-proven; not expected to trigger) ======

__global__ void k_dinv_i(const int* __restrict__ deg, float* __restrict__ dinv, int N) {
    int i = blockIdx.x * blockDim.x + threadIdx.x;
    if (i < N) dinv[i] = rsqrtf((float)deg[i] + 1.0f);
}

template <int D>
__global__ void k_scatter(const int* __restrict__ row, const int* __restrict__ col,
                          const float* __restrict__ dinv, const float* __restrict__ hin,
                          float* __restrict__ agg, int E) {
    int idx = blockIdx.x * blockDim.x + threadIdx.x;
    int e = idx / D, d = idx % D;
    if (e >= E) return;
    int r = row[e], c = col[e];
    float nrm = dinv[r] * dinv[c];
    atomicAdd(&agg[(long)c * D + d], hin[(long)r * D + d] * nrm);
}

template <int D, bool RELU>
__global__ void k_finish(const float* __restrict__ hproj, const float* __restrict__ dinv,
                         const float* __restrict__ bias, float* __restrict__ agg, int N) {
    int idx = blockIdx.x * blockDim.x + threadIdx.x;
    if (idx >= N * D) return;
    int i = idx / D, d = idx % D;
    float di = dinv[i];
    float v = agg[idx] + hproj[idx] * di * di + bias[d];
    agg[idx] = RELU ? fmaxf(v, 0.f) : v;
}

// ================= decode (R4, unchanged): out[i][j] = dot(z[i], z[j]) =======
// 128x128 block tile, 256 threads, 8x8 register tile, k-major LDS [k][row].
#define DT 128

__global__ void k_decode(const float* __restrict__ z, float* __restrict__ out, int N) {
    __shared__ float ziT[16][DT];
    __shared__ float zjT[16][DT];
    int bi = blockIdx.y * DT, bj = blockIdx.x * DT;
    int t = threadIdx.x;

    {
        int r = t & 127;
        int gi = (t < 128 ? bi : bj) + r;
        float4 v0 = make_float4(0.f, 0.f, 0.f, 0.f), v1 = v0, v2 = v0, v3 = v0;
        if (gi < N) {
            const float4* zp = reinterpret_cast<const float4*>(z + (long)gi * 16);
            v0 = zp[0]; v1 = zp[1]; v2 = zp[2]; v3 = zp[3];
        }
        float vals[16] = {v0.x, v0.y, v0.z, v0.w, v1.x, v1.y, v1.z, v1.w,
                          v2.x, v2.y, v2.z, v2.w, v3.x, v3.y, v3.z, v3.w};
        float (*dst)[DT] = (t < 128) ? ziT : zjT;
#pragma unroll
        for (int k = 0; k < 16; ++k) dst[k][r] = vals[k];
    }
    __syncthreads();

    int tx = t & 15, ty = t >> 4;
    float acc[8][8] = {};
#pragma unroll 4
    for (int k = 0; k < 16; ++k) {
        float a[8], b[8];
        float4 a0 = *reinterpret_cast<const float4*>(&ziT[k][ty * 8]);
        float4 a1 = *reinterpret_cast<const float4*>(&ziT[k][ty * 8 + 4]);
        float4 b0 = *reinterpret_cast<const float4*>(&zjT[k][tx * 8]);
        float4 b1 = *reinterpret_cast<const float4*>(&zjT[k][tx * 8 + 4]);
        a[0]=a0.x; a[1]=a0.y; a[2]=a0.z; a[3]=a0.w; a[4]=a1.x; a[5]=a1.y; a[6]=a1.z; a[7]=a1.w;
        b[0]=b0.x; b[1]=b0.y; b[2]=b0.z; b[3]=b0.w; b[4]=b1.x; b[5]=b1.y; b[6]=b1.z; b[7]=b1.w;
#pragma unroll
        for (int u = 0; u < 8; ++u)
#pragma unroll
            for (int v = 0; v < 8; ++v)
                acc[u][v] = fmaf(a[u], b[v], acc[u][v]);
    }

#pragma unroll
    for (int u = 0; u < 8; ++u) {
        int gi = bi + ty * 8 + u;
        if (gi >= N) continue;
        int gj = bj + tx * 8;
        long base = (long)gi * N + gj;
        if (gj + 7 < N) {
            *reinterpret_cast<float4*>(&out[base]) =
                make_float4(acc[u][0], acc[u][1], acc[u][2], acc[u][3]);
            *reinterpret_cast<float4*>(&out[base + 4]) =
                make_float4(acc[u][4], acc[u][5], acc[u][6], acc[u][7]);
        } else {
            for (int v2 = 0; v2 < 8; ++v2)
                if (gj + v2 < N) out[base + v2] = acc[u][v2];
        }
    }
}

// ================= launch =================

extern "C" void kernel_launch(void* const* d_in, const int* in_sizes, int n_in,
                              void* d_out, int out_size, void* d_ws, size_t ws_size,
                              hipStream_t stream) {
    const float* x  = (const float*)d_in[0];
    const int*   ei = (const int*)d_in[1];
    const float* W1 = (const float*)d_in[2];
    const float* b1 = (const float*)d_in[3];
    const float* W2 = (const float*)d_in[4];
    const float* b2 = (const float*)d_in[5];
    float* out = (float*)d_out;

    const int N = in_sizes[0] / IN_DIM;   // 10000
    const int E = in_sizes[1] / 2;        // 640000
    const int* row = ei;
    const int* col = ei + E;

    // region sizes in elems, each padded to a multiple of 16 elems (64B)
    const long SZ_DEG = (N + 15) & ~15L;        // 10000
    const long SZ_RP  = (N + 1 + 15) & ~15L;    // 10016
    const long SZ_CUR = SZ_DEG;                 // 10000
    const long SZ_CSR = (E + 15) & ~15L;        // 640000
    const long SZ_DI  = SZ_DEG;                 // 10000
    const long need = SZ_DEG + SZ_RP + SZ_CUR + SZ_CSR + SZ_DI
                    + 2L * N * H1 + 2L * N * H2;

    if (ws_size >= (size_t)need * 4) {
        // ---- CSR gather path ----
        int*   deg     = (int*)d_ws;
        int*   row_ptr = deg + SZ_DEG;
        int*   cursor  = row_ptr + SZ_RP;
        int*   csr_src = cursor + SZ_CUR;
        float* dinv    = (float*)(csr_src + SZ_CSR);
        float* h       = dinv + SZ_DI;       // (x@W1)*dinv     (N*H1)
        float* h1      = h + (long)N * H1;   // layer-1 out     (N*H1)
        float* h2      = h1 + (long)N * H1;  // (h1@W2)*dinv    (N*H2)
        float* zz      = h2 + (long)N * H2;  // z               (N*H2), 64B-aligned

        hipMemsetAsync(deg, 0, (size_t)N * sizeof(int), stream);
        k_count<<<(E + 255) / 256, 256, 0, stream>>>(col, deg, E);
        k_scan<<<1, SCAN_T, 0, stream>>>(deg, row_ptr, cursor, dinv, N);
        k_fill<<<(E + 255) / 256, 256, 0, stream>>>(row, col, cursor, csr_src, E);

        k_mm<IN_DIM, H1, true><<<((long)N * H1 + 255) / 256, 256, 0, stream>>>(x, W1, dinv, h, N);
        k_gather<H1, true><<<(N + 3) / 4, 256, 0, stream>>>(row_ptr, csr_src, dinv, h, b1, h1, N);

        k_mm<H1, H2, true><<<((long)N * H2 + 255) / 256, 256, 0, stream>>>(h1, W2, dinv, h2, N);
        k_gather<H2, false><<<(N + 3) / 4, 256, 0, stream>>>(row_ptr, csr_src, dinv, h2, b2, zz, N);

        dim3 dgrid((N + DT - 1) / DT, (N + DT - 1) / DT);
        k_decode<<<dgrid, 256, 0, stream>>>(zz, out, N);
    } else {
        // ---- fallback: atomic scatter path ----
        int*   deg  = (int*)d_ws;
        float* dinv = (float*)(deg + SZ_DEG);
        float* h    = dinv + SZ_DI;
        float* h1   = h + (long)N * H1;
        float* h2   = h1 + (long)N * H1;
        float* zz   = h2 + (long)N * H2;

        hipMemsetAsync(deg, 0, (size_t)N * sizeof(int), stream);
        hipMemsetAsync(h1, 0, (size_t)N * H1 * sizeof(float), stream);
        hipMemsetAsync(zz, 0, (size_t)N * H2 * sizeof(float), stream);

        k_count<<<(E + 255) / 256, 256, 0, stream>>>(col, deg, E);
        k_dinv_i<<<(N + 255) / 256, 256, 0, stream>>>(deg, dinv, N);

        k_mm<IN_DIM, H1, false><<<((long)N * H1 + 255) / 256, 256, 0, stream>>>(x, W1, dinv, h, N);
        k_scatter<H1><<<((long)E * H1 + 255) / 256, 256, 0, stream>>>(row, col, dinv, h, h1, E);
        k_finish<H1, true><<<((long)N * H1 + 255) / 256, 256, 0, stream>>>(h, dinv, b1, h1, N);

        k_mm<H1, H2, false><<<((long)N * H2 + 255) / 256, 256, 0, stream>>>(h1, W2, dinv, h2, N);
        k_scatter<H2><<<((long)E * H2 + 255) / 256, 256, 0, stream>>>(row, col, dinv, h2, zz, E);
        k_finish<H2, false><<<((long)N * H2 + 255) / 256, 256, 0, stream>>>(h2, dinv, b2, zz, N);

        dim3 dgrid((N + DT - 1) / DT, (N + DT - 1) / DT);
        k_decode<<<dgrid, 256, 0, stream>>>(zz, out, N);
    }
}

// Round 7
// 246.974 us; speedup vs baseline: 6.9811x; 1.0126x over previous
//
#include <hip/hip_runtime.h>

#define IN_DIM 128
#define H1 32
#define H2 16

// ================= CSR build =================

__global__ void k_count(const int* __restrict__ col, int* __restrict__ deg, int E) {
    int e = blockIdx.x * blockDim.x + threadIdx.x;
    if (e < E) atomicAdd(&deg[col[e]], 1);
}

// single-block scan: row_ptr (exclusive), cursor copy, dinv = rsqrt(deg+1)
#define SCAN_T 1024
__global__ void k_scan(const int* __restrict__ deg, int* __restrict__ row_ptr,
                       int* __restrict__ cursor, float* __restrict__ dinv, int N) {
    __shared__ int sums[SCAN_T];
    int t = threadIdx.x;
    int per = (N + SCAN_T - 1) / SCAN_T;   // 10 for N=10000
    int start = t * per;
    int local[16];
    int s = 0;
    for (int k = 0; k < per && k < 16; ++k) {
        int i = start + k;
        int v = (i < N) ? deg[i] : 0;
        local[k] = s;
        s += v;
    }
    sums[t] = s;
    __syncthreads();
    for (int off = 1; off < SCAN_T; off <<= 1) {
        int v = (t >= off) ? sums[t - off] : 0;
        __syncthreads();
        sums[t] += v;
        __syncthreads();
    }
    int base = (t > 0) ? sums[t - 1] : 0;
    for (int k = 0; k < per && k < 16; ++k) {
        int i = start + k;
        if (i < N) {
            int rp = base + local[k];
            row_ptr[i] = rp;
            cursor[i] = rp;
            dinv[i] = rsqrtf((float)deg[i] + 1.0f);
        }
    }
    if (t == SCAN_T - 1) row_ptr[N] = sums[t];
}

__global__ void k_fill(const int* __restrict__ row, const int* __restrict__ col,
                       int* __restrict__ cursor, int* __restrict__ csr_src, int E) {
    int e = blockIdx.x * blockDim.x + threadIdx.x;
    if (e < E) {
        int c = col[e];
        int pos = atomicAdd(&cursor[c], 1);
        csr_src[pos] = row[e];
    }
}

// ================= dense projection (float4 loads; optional *dinv epilogue) ==
// SCALE=true: hout[i][d] = (xin[i] @ W)[d] * dinv[i]   (pre-scaled for gather)
template <int KD, int OD, bool SCALE>
__global__ void k_mm(const float* __restrict__ xin, const float* __restrict__ W,
                     const float* __restrict__ dinv, float* __restrict__ hout, int N) {
    __shared__ float Ws[KD * OD];
    for (int t = threadIdx.x; t < KD * OD; t += blockDim.x) Ws[t] = W[t];
    __syncthreads();
    int idx = blockIdx.x * blockDim.x + threadIdx.x;
    int i = idx / OD, d = idx % OD;
    if (i >= N) return;
    const float4* xr = reinterpret_cast<const float4*>(xin + (long)i * KD);
    float acc = 0.f;
#pragma unroll
    for (int k4 = 0; k4 < KD / 4; ++k4) {
        float4 xv = xr[k4];
        acc = fmaf(xv.x, Ws[(4 * k4 + 0) * OD + d], acc);
        acc = fmaf(xv.y, Ws[(4 * k4 + 1) * OD + d], acc);
        acc = fmaf(xv.z, Ws[(4 * k4 + 2) * OD + d], acc);
        acc = fmaf(xv.w, Ws[(4 * k4 + 3) * OD + d], acc);
    }
    hout[idx] = SCALE ? acc * dinv[i] : acc;
}

// ================= CSR gather, float4 lanes ==================================
// out[c][:] = dinv[c] * (sum_{r in in(c)} hp[r][:] + hp[c][:]) + b[:]
// wave = 64 lanes = (64/(D/4)) edge-subgroups x (D/4) float4-chunks.
// D=32: 8 edges/iter, 16B/lane -> 1KB/wave-load; 4x unroll -> 4KB in flight.
template <int D, bool RELU>
__global__ void k_gather(const int* __restrict__ row_ptr, const int* __restrict__ csr_src,
                         const float* __restrict__ dinv, const float* __restrict__ hp,
                         const float* __restrict__ bias, float* __restrict__ out, int N) {
    constexpr int C4  = D / 4;        // float4 chunks per row (8 or 4)
    constexpr int SUB = 64 / C4;      // edges per wave-iteration (8 or 16)
    int c = blockIdx.x * (blockDim.x >> 6) + (threadIdx.x >> 6);
    if (c >= N) return;
    int lane = threadIdx.x & 63;
    int sub = lane / C4, d4 = lane % C4;
    int beg = row_ptr[c], end = row_ptr[c + 1];
    const float4* hp4 = reinterpret_cast<const float4*>(hp);

    float4 A0 = make_float4(0.f, 0.f, 0.f, 0.f), A1 = A0, A2 = A0, A3 = A0;
    int k = beg + sub;
    for (; k + 3 * SUB < end; k += 4 * SUB) {   // 4 independent row-loads in flight
        int s0 = csr_src[k];
        int s1 = csr_src[k + SUB];
        int s2 = csr_src[k + 2 * SUB];
        int s3 = csr_src[k + 3 * SUB];
        float4 v0 = hp4[(long)s0 * C4 + d4];
        float4 v1 = hp4[(long)s1 * C4 + d4];
        float4 v2 = hp4[(long)s2 * C4 + d4];
        float4 v3 = hp4[(long)s3 * C4 + d4];
        A0.x += v0.x; A0.y += v0.y; A0.z += v0.z; A0.w += v0.w;
        A1.x += v1.x; A1.y += v1.y; A1.z += v1.z; A1.w += v1.w;
        A2.x += v2.x; A2.y += v2.y; A2.z += v2.z; A2.w += v2.w;
        A3.x += v3.x; A3.y += v3.y; A3.z += v3.z; A3.w += v3.w;
    }
    for (; k < end; k += SUB) {
        float4 v = hp4[(long)csr_src[k] * C4 + d4];
        A0.x += v.x; A0.y += v.y; A0.z += v.z; A0.w += v.w;
    }
    float4 acc;
    acc.x = (A0.x + A1.x) + (A2.x + A3.x);
    acc.y = (A0.y + A1.y) + (A2.y + A3.y);
    acc.z = (A0.z + A1.z) + (A2.z + A3.z);
    acc.w = (A0.w + A1.w) + (A2.w + A3.w);
#pragma unroll
    for (int off = C4; off < 64; off <<= 1) {
        acc.x += __shfl_xor(acc.x, off, 64);
        acc.y += __shfl_xor(acc.y, off, 64);
        acc.z += __shfl_xor(acc.z, off, 64);
        acc.w += __shfl_xor(acc.w, off, 64);
    }
    if (lane < C4) {
        float di = dinv[c];
        float4 self = hp4[(long)c * C4 + d4];
        float4 bv = reinterpret_cast<const float4*>(bias)[d4];
        float4 v;
        v.x = fmaf(di, acc.x + self.x, bv.x);
        v.y = fmaf(di, acc.y + self.y, bv.y);
        v.z = fmaf(di, acc.z + self.z, bv.z);
        v.w = fmaf(di, acc.w + self.w, bv.w);
        if (RELU) {
            v.x = fmaxf(v.x, 0.f); v.y = fmaxf(v.y, 0.f);
            v.z = fmaxf(v.z, 0.f); v.w = fmaxf(v.w, 0.f);
        }
        reinterpret_cast<float4*>(out + (long)c * D)[d4] = v;
    }
}

// ================= atomic fallback (R3-proven; not expected to trigger) ======

__global__ void k_dinv_i(const int* __restrict__ deg, float* __restrict__ dinv, int N) {
    int i = blockIdx.x * blockDim.x + threadIdx.x;
    if (i < N) dinv[i] = rsqrtf((float)deg[i] + 1.0f);
}

template <int D>
__global__ void k_scatter(const int* __restrict__ row, const int* __restrict__ col,
                          const float* __restrict__ dinv, const float* __restrict__ hin,
                          float* __restrict__ agg, int E) {
    int idx = blockIdx.x * blockDim.x + threadIdx.x;
    int e = idx / D, d = idx % D;
    if (e >= E) return;
    int r = row[e], c = col[e];
    float nrm = dinv[r] * dinv[c];
    atomicAdd(&agg[(long)c * D + d], hin[(long)r * D + d] * nrm);
}

template <int D, bool RELU>
__global__ void k_finish(const float* __restrict__ hproj, const float* __restrict__ dinv,
                         const float* __restrict__ bias, float* __restrict__ agg, int N) {
    int idx = blockIdx.x * blockDim.x + threadIdx.x;
    if (idx >= N * D) return;
    int i = idx / D, d = idx % D;
    float di = dinv[i];
    float v = agg[idx] + hproj[idx] * di * di + bias[d];
    agg[idx] = RELU ? fmaxf(v, 0.f) : v;
}

// ================= decode (R4, unchanged): out[i][j] = dot(z[i], z[j]) =======
// 128x128 block tile, 256 threads, 8x8 register tile, k-major LDS [k][row].
#define DT 128

__global__ void k_decode(const float* __restrict__ z, float* __restrict__ out, int N) {
    __shared__ float ziT[16][DT];
    __shared__ float zjT[16][DT];
    int bi = blockIdx.y * DT, bj = blockIdx.x * DT;
    int t = threadIdx.x;

    {
        int r = t & 127;
        int gi = (t < 128 ? bi : bj) + r;
        float4 v0 = make_float4(0.f, 0.f, 0.f, 0.f), v1 = v0, v2 = v0, v3 = v0;
        if (gi < N) {
            const float4* zp = reinterpret_cast<const float4*>(z + (long)gi * 16);
            v0 = zp[0]; v1 = zp[1]; v2 = zp[2]; v3 = zp[3];
        }
        float vals[16] = {v0.x, v0.y, v0.z, v0.w, v1.x, v1.y, v1.z, v1.w,
                          v2.x, v2.y, v2.z, v2.w, v3.x, v3.y, v3.z, v3.w};
        float (*dst)[DT] = (t < 128) ? ziT : zjT;
#pragma unroll
        for (int k = 0; k < 16; ++k) dst[k][r] = vals[k];
    }
    __syncthreads();

    int tx = t & 15, ty = t >> 4;
    float acc[8][8] = {};
#pragma unroll 4
    for (int k = 0; k < 16; ++k) {
        float a[8], b[8];
        float4 a0 = *reinterpret_cast<const float4*>(&ziT[k][ty * 8]);
        float4 a1 = *reinterpret_cast<const float4*>(&ziT[k][ty * 8 + 4]);
        float4 b0 = *reinterpret_cast<const float4*>(&zjT[k][tx * 8]);
        float4 b1 = *reinterpret_cast<const float4*>(&zjT[k][tx * 8 + 4]);
        a[0]=a0.x; a[1]=a0.y; a[2]=a0.z; a[3]=a0.w; a[4]=a1.x; a[5]=a1.y; a[6]=a1.z; a[7]=a1.w;
        b[0]=b0.x; b[1]=b0.y; b[2]=b0.z; b[3]=b0.w; b[4]=b1.x; b[5]=b1.y; b[6]=b1.z; b[7]=b1.w;
#pragma unroll
        for (int u = 0; u < 8; ++u)
#pragma unroll
            for (int v = 0; v < 8; ++v)
                acc[u][v] = fmaf(a[u], b[v], acc[u][v]);
    }

#pragma unroll
    for (int u = 0; u < 8; ++u) {
        int gi = bi + ty * 8 + u;
        if (gi >= N) continue;
        int gj = bj + tx * 8;
        long base = (long)gi * N + gj;
        if (gj + 7 < N) {
            *reinterpret_cast<float4*>(&out[base]) =
                make_float4(acc[u][0], acc[u][1], acc[u][2], acc[u][3]);
            *reinterpret_cast<float4*>(&out[base + 4]) =
                make_float4(acc[u][4], acc[u][5], acc[u][6], acc[u][7]);
        } else {
            for (int v2 = 0; v2 < 8; ++v2)
                if (gj + v2 < N) out[base + v2] = acc[u][v2];
        }
    }
}

// ================= launch =================

extern "C" void kernel_launch(void* const* d_in, const int* in_sizes, int n_in,
                              void* d_out, int out_size, void* d_ws, size_t ws_size,
                              hipStream_t stream) {
    const float* x  = (const float*)d_in[0];
    const int*   ei = (const int*)d_in[1];
    const float* W1 = (const float*)d_in[2];
    const float* b1 = (const float*)d_in[3];
    const float* W2 = (const float*)d_in[4];
    const float* b2 = (const float*)d_in[5];
    float* out = (float*)d_out;

    const int N = in_sizes[0] / IN_DIM;   // 10000
    const int E = in_sizes[1] / 2;        // 640000
    const int* row = ei;
    const int* col = ei + E;

    // region sizes in elems, each padded to a multiple of 16 elems (64B)
    const long SZ_DEG = (N + 15) & ~15L;        // 10000
    const long SZ_RP  = (N + 1 + 15) & ~15L;    // 10016
    const long SZ_CUR = SZ_DEG;                 // 10000
    const long SZ_CSR = (E + 15) & ~15L;        // 640000
    const long SZ_DI  = SZ_DEG;                 // 10000
    const long need = SZ_DEG + SZ_RP + SZ_CUR + SZ_CSR + SZ_DI
                    + 2L * N * H1 + 2L * N * H2;

    if (ws_size >= (size_t)need * 4) {
        // ---- CSR gather path ----
        int*   deg     = (int*)d_ws;
        int*   row_ptr = deg + SZ_DEG;
        int*   cursor  = row_ptr + SZ_RP;
        int*   csr_src = cursor + SZ_CUR;
        float* dinv    = (float*)(csr_src + SZ_CSR);
        float* h       = dinv + SZ_DI;       // (x@W1)*dinv     (N*H1)
        float* h1      = h + (long)N * H1;   // layer-1 out     (N*H1)
        float* h2      = h1 + (long)N * H1;  // (h1@W2)*dinv    (N*H2)
        float* zz      = h2 + (long)N * H2;  // z               (N*H2), 64B-aligned

        hipMemsetAsync(deg, 0, (size_t)N * sizeof(int), stream);
        k_count<<<(E + 255) / 256, 256, 0, stream>>>(col, deg, E);
        k_scan<<<1, SCAN_T, 0, stream>>>(deg, row_ptr, cursor, dinv, N);
        k_fill<<<(E + 255) / 256, 256, 0, stream>>>(row, col, cursor, csr_src, E);

        k_mm<IN_DIM, H1, true><<<((long)N * H1 + 255) / 256, 256, 0, stream>>>(x, W1, dinv, h, N);
        k_gather<H1, true><<<(N + 3) / 4, 256, 0, stream>>>(row_ptr, csr_src, dinv, h, b1, h1, N);

        k_mm<H1, H2, true><<<((long)N * H2 + 255) / 256, 256, 0, stream>>>(h1, W2, dinv, h2, N);
        k_gather<H2, false><<<(N + 3) / 4, 256, 0, stream>>>(row_ptr, csr_src, dinv, h2, b2, zz, N);

        dim3 dgrid((N + DT - 1) / DT, (N + DT - 1) / DT);
        k_decode<<<dgrid, 256, 0, stream>>>(zz, out, N);
    } else {
        // ---- fallback: atomic scatter path ----
        int*   deg  = (int*)d_ws;
        float* dinv = (float*)(deg + SZ_DEG);
        float* h    = dinv + SZ_DI;
        float* h1   = h + (long)N * H1;
        float* h2   = h1 + (long)N * H1;
        float* zz   = h2 + (long)N * H2;

        hipMemsetAsync(deg, 0, (size_t)N * sizeof(int), stream);
        hipMemsetAsync(h1, 0, (size_t)N * H1 * sizeof(float), stream);
        hipMemsetAsync(zz, 0, (size_t)N * H2 * sizeof(float), stream);

        k_count<<<(E + 255) / 256, 256, 0, stream>>>(col, deg, E);
        k_dinv_i<<<(N + 255) / 256, 256, 0, stream>>>(deg, dinv, N);

        k_mm<IN_DIM, H1, false><<<((long)N * H1 + 255) / 256, 256, 0, stream>>>(x, W1, dinv, h, N);
        k_scatter<H1><<<((long)E * H1 + 255) / 256, 256, 0, stream>>>(row, col, dinv, h, h1, E);
        k_finish<H1, true><<<((long)N * H1 + 255) / 256, 256, 0, stream>>>(h, dinv, b1, h1, N);

        k_mm<H1, H2, false><<<((long)N * H2 + 255) / 256, 256, 0, stream>>>(h1, W2, dinv, h2, N);
        k_scatter<H2><<<((long)E * H2 + 255) / 256, 256, 0, stream>>>(row, col, dinv, h2, zz, E);
        k_finish<H2, false><<<((long)N * H2 + 255) / 256, 256, 0, stream>>>(h2, dinv, b2, zz, N);

        dim3 dgrid((N + DT - 1) / DT, (N + DT - 1) / DT);
        k_decode<<<dgrid, 256, 0, stream>>>(zz, out, N);
    }
}

// Round 8
// 236.282 us; speedup vs baseline: 7.2970x; 1.0452x over previous
//
#include <hip/hip_runtime.h>

#define IN_DIM 128
#define H1 32
#define H2 16

// ================= CSR build =================

__global__ void k_count(const int* __restrict__ col, int* __restrict__ deg, int E) {
    int e = blockIdx.x * blockDim.x + threadIdx.x;
    if (e < E) atomicAdd(&deg[col[e]], 1);
}

// single-block scan: row_ptr (exclusive), cursor copy, dinv = rsqrt(deg+1)
#define SCAN_T 1024
__global__ void k_scan(const int* __restrict__ deg, int* __restrict__ row_ptr,
                       int* __restrict__ cursor, float* __restrict__ dinv, int N) {
    __shared__ int sums[SCAN_T];
    int t = threadIdx.x;
    int per = (N + SCAN_T - 1) / SCAN_T;   // 10 for N=10000
    int start = t * per;
    int local[16];
    int s = 0;
    for (int k = 0; k < per && k < 16; ++k) {
        int i = start + k;
        int v = (i < N) ? deg[i] : 0;
        local[k] = s;
        s += v;
    }
    sums[t] = s;
    __syncthreads();
    for (int off = 1; off < SCAN_T; off <<= 1) {
        int v = (t >= off) ? sums[t - off] : 0;
        __syncthreads();
        sums[t] += v;
        __syncthreads();
    }
    int base = (t > 0) ? sums[t - 1] : 0;
    for (int k = 0; k < per && k < 16; ++k) {
        int i = start + k;
        if (i < N) {
            int rp = base + local[k];
            row_ptr[i] = rp;
            cursor[i] = rp;
            dinv[i] = rsqrtf((float)deg[i] + 1.0f);
        }
    }
    if (t == SCAN_T - 1) row_ptr[N] = sums[t];
}

// ================= fused: CSR fill (blocks 0..FB-1)  ||  mm1 (blocks FB..) ===
// mm1 part: h'[i][d] = (x[i] @ W1)[d] * dinv[i], 8 nodes/block, x staged in LDS
#define XNODES 8
__global__ void k_fill_mm1(const int* __restrict__ row, const int* __restrict__ col,
                           int* __restrict__ cursor, int* __restrict__ csr_src, int E,
                           const float* __restrict__ x, const float* __restrict__ W1,
                           const float* __restrict__ dinv, float* __restrict__ hout,
                           int N, int fillBlocks) {
    __shared__ float Ws[IN_DIM * H1];          // 16 KB
    __shared__ float xs[XNODES][IN_DIM];       // 4 KB
    if ((int)blockIdx.x < fillBlocks) {
        int e = blockIdx.x * blockDim.x + threadIdx.x;
        if (e < E) {
            int c = col[e];
            int pos = atomicAdd(&cursor[c], 1);
            csr_src[pos] = row[e];
        }
        return;   // whole block exits; no barrier crossed
    }
    int t = threadIdx.x;
    int i0 = ((int)blockIdx.x - fillBlocks) * XNODES;
    const float4* W4 = reinterpret_cast<const float4*>(W1);
    float4* Ws4 = reinterpret_cast<float4*>(Ws);
#pragma unroll
    for (int i = t; i < IN_DIM * H1 / 4; i += 256) Ws4[i] = W4[i];
    const float4* xg = reinterpret_cast<const float4*>(x + (long)i0 * IN_DIM);
    float4* xs4 = reinterpret_cast<float4*>(xs);
    xs4[t] = xg[t];   // XNODES*IN_DIM/4 == 256 exactly
    __syncthreads();
    int n = t >> 5, d = t & 31;
    float acc = 0.f;
#pragma unroll 8
    for (int k = 0; k < IN_DIM; ++k) acc = fmaf(xs[n][k], Ws[k * H1 + d], acc);
    int i = i0 + n;
    if (i < N) hout[(long)i * H1 + d] = acc * dinv[i];
}

// ================= fused gather1 + mm2 =======================================
// wave w handles node c: h1[c] = relu(dinv[c]*(sum hp[src] + hp[c]) + b1)  (in-wave)
// then h2p[c][j] = (h1[c] @ W2)[j] * dinv[c]   -> global
__global__ void k_g1mm2(const int* __restrict__ row_ptr, const int* __restrict__ csr_src,
                        const float* __restrict__ dinv, const float* __restrict__ hp,
                        const float* __restrict__ b1, const float* __restrict__ W2,
                        float* __restrict__ h2p, int N) {
    __shared__ float W2s[H1 * H2];     // 2 KB
    __shared__ float h1s[4][H1];       // per-wave slot
    int t = threadIdx.x;
    for (int i = t; i < H1 * H2; i += blockDim.x) W2s[i] = W2[i];
    __syncthreads();
    int wv = t >> 6;
    int lane = t & 63;
    int c = blockIdx.x * 4 + wv;
    bool active = (c < N);
    int cc = active ? c : (N - 1);     // clamp: inactive waves do harmless reads
    constexpr int C4 = H1 / 4;         // 8 float4 chunks
    constexpr int SUB = 64 / C4;       // 8 edges per wave-iter
    int sub = lane / C4, d4 = lane % C4;
    int beg = row_ptr[cc], end = row_ptr[cc + 1];
    const float4* hp4 = reinterpret_cast<const float4*>(hp);

    float4 A0 = make_float4(0.f, 0.f, 0.f, 0.f), A1 = A0, A2 = A0, A3 = A0;
    int k = beg + sub;
    for (; k + 3 * SUB < end; k += 4 * SUB) {
        int s0 = csr_src[k];
        int s1 = csr_src[k + SUB];
        int s2 = csr_src[k + 2 * SUB];
        int s3 = csr_src[k + 3 * SUB];
        float4 v0 = hp4[(long)s0 * C4 + d4];
        float4 v1 = hp4[(long)s1 * C4 + d4];
        float4 v2 = hp4[(long)s2 * C4 + d4];
        float4 v3 = hp4[(long)s3 * C4 + d4];
        A0.x += v0.x; A0.y += v0.y; A0.z += v0.z; A0.w += v0.w;
        A1.x += v1.x; A1.y += v1.y; A1.z += v1.z; A1.w += v1.w;
        A2.x += v2.x; A2.y += v2.y; A2.z += v2.z; A2.w += v2.w;
        A3.x += v3.x; A3.y += v3.y; A3.z += v3.z; A3.w += v3.w;
    }
    for (; k < end; k += SUB) {
        float4 v = hp4[(long)csr_src[k] * C4 + d4];
        A0.x += v.x; A0.y += v.y; A0.z += v.z; A0.w += v.w;
    }
    float4 acc;
    acc.x = (A0.x + A1.x) + (A2.x + A3.x);
    acc.y = (A0.y + A1.y) + (A2.y + A3.y);
    acc.z = (A0.z + A1.z) + (A2.z + A3.z);
    acc.w = (A0.w + A1.w) + (A2.w + A3.w);
#pragma unroll
    for (int off = C4; off < 64; off <<= 1) {
        acc.x += __shfl_xor(acc.x, off, 64);
        acc.y += __shfl_xor(acc.y, off, 64);
        acc.z += __shfl_xor(acc.z, off, 64);
        acc.w += __shfl_xor(acc.w, off, 64);
    }
    if (lane < C4) {
        float di = dinv[cc];
        float4 self = hp4[(long)cc * C4 + d4];
        float4 bv = reinterpret_cast<const float4*>(b1)[d4];
        float4 v;
        v.x = fmaxf(fmaf(di, acc.x + self.x, bv.x), 0.f);
        v.y = fmaxf(fmaf(di, acc.y + self.y, bv.y), 0.f);
        v.z = fmaxf(fmaf(di, acc.z + self.z, bv.z), 0.f);
        v.w = fmaxf(fmaf(di, acc.w + self.w, bv.w), 0.f);
        reinterpret_cast<float4*>(h1s[wv])[d4] = v;
    }
    __syncthreads();   // all threads reach (no early returns)
    if (active && lane < H2) {
        float z = 0.f;
#pragma unroll
        for (int kk = 0; kk < H1; ++kk) z = fmaf(h1s[wv][kk], W2s[kk * H2 + lane], z);
        h2p[(long)c * H2 + lane] = z * dinv[c];
    }
}

// ================= CSR gather, float4 lanes (layer 2) ========================
template <int D, bool RELU>
__global__ void k_gather(const int* __restrict__ row_ptr, const int* __restrict__ csr_src,
                         const float* __restrict__ dinv, const float* __restrict__ hp,
                         const float* __restrict__ bias, float* __restrict__ out, int N) {
    constexpr int C4  = D / 4;
    constexpr int SUB = 64 / C4;
    int c = blockIdx.x * (blockDim.x >> 6) + (threadIdx.x >> 6);
    if (c >= N) return;
    int lane = threadIdx.x & 63;
    int sub = lane / C4, d4 = lane % C4;
    int beg = row_ptr[c], end = row_ptr[c + 1];
    const float4* hp4 = reinterpret_cast<const float4*>(hp);

    float4 A0 = make_float4(0.f, 0.f, 0.f, 0.f), A1 = A0, A2 = A0, A3 = A0;
    int k = beg + sub;
    for (; k + 3 * SUB < end; k += 4 * SUB) {
        int s0 = csr_src[k];
        int s1 = csr_src[k + SUB];
        int s2 = csr_src[k + 2 * SUB];
        int s3 = csr_src[k + 3 * SUB];
        float4 v0 = hp4[(long)s0 * C4 + d4];
        float4 v1 = hp4[(long)s1 * C4 + d4];
        float4 v2 = hp4[(long)s2 * C4 + d4];
        float4 v3 = hp4[(long)s3 * C4 + d4];
        A0.x += v0.x; A0.y += v0.y; A0.z += v0.z; A0.w += v0.w;
        A1.x += v1.x; A1.y += v1.y; A1.z += v1.z; A1.w += v1.w;
        A2.x += v2.x; A2.y += v2.y; A2.z += v2.z; A2.w += v2.w;
        A3.x += v3.x; A3.y += v3.y; A3.z += v3.z; A3.w += v3.w;
    }
    for (; k < end; k += SUB) {
        float4 v = hp4[(long)csr_src[k] * C4 + d4];
        A0.x += v.x; A0.y += v.y; A0.z += v.z; A0.w += v.w;
    }
    float4 acc;
    acc.x = (A0.x + A1.x) + (A2.x + A3.x);
    acc.y = (A0.y + A1.y) + (A2.y + A3.y);
    acc.z = (A0.z + A1.z) + (A2.z + A3.z);
    acc.w = (A0.w + A1.w) + (A2.w + A3.w);
#pragma unroll
    for (int off = C4; off < 64; off <<= 1) {
        acc.x += __shfl_xor(acc.x, off, 64);
        acc.y += __shfl_xor(acc.y, off, 64);
        acc.z += __shfl_xor(acc.z, off, 64);
        acc.w += __shfl_xor(acc.w, off, 64);
    }
    if (lane < C4) {
        float di = dinv[c];
        float4 self = hp4[(long)c * C4 + d4];
        float4 bv = reinterpret_cast<const float4*>(bias)[d4];
        float4 v;
        v.x = fmaf(di, acc.x + self.x, bv.x);
        v.y = fmaf(di, acc.y + self.y, bv.y);
        v.z = fmaf(di, acc.z + self.z, bv.z);
        v.w = fmaf(di, acc.w + self.w, bv.w);
        if (RELU) {
            v.x = fmaxf(v.x, 0.f); v.y = fmaxf(v.y, 0.f);
            v.z = fmaxf(v.z, 0.f); v.w = fmaxf(v.w, 0.f);
        }
        reinterpret_cast<float4*>(out + (long)c * D)[d4] = v;
    }
}

// ================= atomic fallback path =================

template <int KD, int OD, bool SCALE>
__global__ void k_mm(const float* __restrict__ xin, const float* __restrict__ W,
                     const float* __restrict__ dinv, float* __restrict__ hout, int N) {
    __shared__ float Ws[KD * OD];
    for (int t = threadIdx.x; t < KD * OD; t += blockDim.x) Ws[t] = W[t];
    __syncthreads();
    int idx = blockIdx.x * blockDim.x + threadIdx.x;
    int i = idx / OD, d = idx % OD;
    if (i >= N) return;
    const float4* xr = reinterpret_cast<const float4*>(xin + (long)i * KD);
    float acc = 0.f;
#pragma unroll
    for (int k4 = 0; k4 < KD / 4; ++k4) {
        float4 xv = xr[k4];
        acc = fmaf(xv.x, Ws[(4 * k4 + 0) * OD + d], acc);
        acc = fmaf(xv.y, Ws[(4 * k4 + 1) * OD + d], acc);
        acc = fmaf(xv.z, Ws[(4 * k4 + 2) * OD + d], acc);
        acc = fmaf(xv.w, Ws[(4 * k4 + 3) * OD + d], acc);
    }
    hout[idx] = SCALE ? acc * dinv[i] : acc;
}

__global__ void k_dinv_i(const int* __restrict__ deg, float* __restrict__ dinv, int N) {
    int i = blockIdx.x * blockDim.x + threadIdx.x;
    if (i < N) dinv[i] = rsqrtf((float)deg[i] + 1.0f);
}

template <int D>
__global__ void k_scatter(const int* __restrict__ row, const int* __restrict__ col,
                          const float* __restrict__ dinv, const float* __restrict__ hin,
                          float* __restrict__ agg, int E) {
    int idx = blockIdx.x * blockDim.x + threadIdx.x;
    int e = idx / D, d = idx % D;
    if (e >= E) return;
    int r = row[e], c = col[e];
    float nrm = dinv[r] * dinv[c];
    atomicAdd(&agg[(long)c * D + d], hin[(long)r * D + d] * nrm);
}

template <int D, bool RELU>
__global__ void k_finish(const float* __restrict__ hproj, const float* __restrict__ dinv,
                         const float* __restrict__ bias, float* __restrict__ agg, int N) {
    int idx = blockIdx.x * blockDim.x + threadIdx.x;
    if (idx >= N * D) return;
    int i = idx / D, d = idx % D;
    float di = dinv[i];
    float v = agg[idx] + hproj[idx] * di * di + bias[d];
    agg[idx] = RELU ? fmaxf(v, 0.f) : v;
}

// ================= decode (R4, unchanged): out[i][j] = dot(z[i], z[j]) =======
#define DT 128

__global__ void k_decode(const float* __restrict__ z, float* __restrict__ out, int N) {
    __shared__ float ziT[16][DT];
    __shared__ float zjT[16][DT];
    int bi = blockIdx.y * DT, bj = blockIdx.x * DT;
    int t = threadIdx.x;

    {
        int r = t & 127;
        int gi = (t < 128 ? bi : bj) + r;
        float4 v0 = make_float4(0.f, 0.f, 0.f, 0.f), v1 = v0, v2 = v0, v3 = v0;
        if (gi < N) {
            const float4* zp = reinterpret_cast<const float4*>(z + (long)gi * 16);
            v0 = zp[0]; v1 = zp[1]; v2 = zp[2]; v3 = zp[3];
        }
        float vals[16] = {v0.x, v0.y, v0.z, v0.w, v1.x, v1.y, v1.z, v1.w,
                          v2.x, v2.y, v2.z, v2.w, v3.x, v3.y, v3.z, v3.w};
        float (*dst)[DT] = (t < 128) ? ziT : zjT;
#pragma unroll
        for (int k = 0; k < 16; ++k) dst[k][r] = vals[k];
    }
    __syncthreads();

    int tx = t & 15, ty = t >> 4;
    float acc[8][8] = {};
#pragma unroll 4
    for (int k = 0; k < 16; ++k) {
        float a[8], b[8];
        float4 a0 = *reinterpret_cast<const float4*>(&ziT[k][ty * 8]);
        float4 a1 = *reinterpret_cast<const float4*>(&ziT[k][ty * 8 + 4]);
        float4 b0 = *reinterpret_cast<const float4*>(&zjT[k][tx * 8]);
        float4 b1 = *reinterpret_cast<const float4*>(&zjT[k][tx * 8 + 4]);
        a[0]=a0.x; a[1]=a0.y; a[2]=a0.z; a[3]=a0.w; a[4]=a1.x; a[5]=a1.y; a[6]=a1.z; a[7]=a1.w;
        b[0]=b0.x; b[1]=b0.y; b[2]=b0.z; b[3]=b0.w; b[4]=b1.x; b[5]=b1.y; b[6]=b1.z; b[7]=b1.w;
#pragma unroll
        for (int u = 0; u < 8; ++u)
#pragma unroll
            for (int v = 0; v < 8; ++v)
                acc[u][v] = fmaf(a[u], b[v], acc[u][v]);
    }

#pragma unroll
    for (int u = 0; u < 8; ++u) {
        int gi = bi + ty * 8 + u;
        if (gi >= N) continue;
        int gj = bj + tx * 8;
        long base = (long)gi * N + gj;
        if (gj + 7 < N) {
            *reinterpret_cast<float4*>(&out[base]) =
                make_float4(acc[u][0], acc[u][1], acc[u][2], acc[u][3]);
            *reinterpret_cast<float4*>(&out[base + 4]) =
                make_float4(acc[u][4], acc[u][5], acc[u][6], acc[u][7]);
        } else {
            for (int v2 = 0; v2 < 8; ++v2)
                if (gj + v2 < N) out[base + v2] = acc[u][v2];
        }
    }
}

// ================= launch =================

extern "C" void kernel_launch(void* const* d_in, const int* in_sizes, int n_in,
                              void* d_out, int out_size, void* d_ws, size_t ws_size,
                              hipStream_t stream) {
    const float* x  = (const float*)d_in[0];
    const int*   ei = (const int*)d_in[1];
    const float* W1 = (const float*)d_in[2];
    const float* b1 = (const float*)d_in[3];
    const float* W2 = (const float*)d_in[4];
    const float* b2 = (const float*)d_in[5];
    float* out = (float*)d_out;

    const int N = in_sizes[0] / IN_DIM;   // 10000
    const int E = in_sizes[1] / 2;        // 640000
    const int* row = ei;
    const int* col = ei + E;

    const long SZ_DEG = (N + 15) & ~15L;
    const long SZ_RP  = (N + 1 + 15) & ~15L;
    const long SZ_CUR = SZ_DEG;
    const long SZ_CSR = (E + 15) & ~15L;
    const long SZ_DI  = SZ_DEG;
    const long need = SZ_DEG + SZ_RP + SZ_CUR + SZ_CSR + SZ_DI
                    + 2L * N * H1 + 2L * N * H2;

    if (ws_size >= (size_t)need * 4) {
        // ---- CSR fused path (7 dispatches incl. decode) ----
        int*   deg     = (int*)d_ws;
        int*   row_ptr = deg + SZ_DEG;
        int*   cursor  = row_ptr + SZ_RP;
        int*   csr_src = cursor + SZ_CUR;
        float* dinv    = (float*)(csr_src + SZ_CSR);
        float* h       = dinv + SZ_DI;       // (x@W1)*dinv   (N*H1)
        float* h2p     = h + 2L * N * H1;    // (h1@W2)*dinv  (N*H2)  [h1 slot skipped]
        float* zz      = h2p + (long)N * H2; // z             (N*H2), 64B-aligned

        hipMemsetAsync(deg, 0, (size_t)N * sizeof(int), stream);
        k_count<<<(E + 255) / 256, 256, 0, stream>>>(col, deg, E);
        k_scan<<<1, SCAN_T, 0, stream>>>(deg, row_ptr, cursor, dinv, N);

        int fillBlocks = (E + 255) / 256;                    // 2500
        int mmBlocks   = (N + XNODES - 1) / XNODES;          // 1250
        k_fill_mm1<<<fillBlocks + mmBlocks, 256, 0, stream>>>(
            row, col, cursor, csr_src, E, x, W1, dinv, h, N, fillBlocks);

        k_g1mm2<<<(N + 3) / 4, 256, 0, stream>>>(row_ptr, csr_src, dinv, h, b1, W2, h2p, N);
        k_gather<H2, false><<<(N + 3) / 4, 256, 0, stream>>>(row_ptr, csr_src, dinv, h2p, b2, zz, N);

        dim3 dgrid((N + DT - 1) / DT, (N + DT - 1) / DT);
        k_decode<<<dgrid, 256, 0, stream>>>(zz, out, N);
    } else {
        // ---- fallback: atomic scatter path ----
        int*   deg  = (int*)d_ws;
        float* dinv = (float*)(deg + SZ_DEG);
        float* h    = dinv + SZ_DI;
        float* h1   = h + (long)N * H1;
        float* h2   = h1 + (long)N * H1;
        float* zz   = h2 + (long)N * H2;

        hipMemsetAsync(deg, 0, (size_t)N * sizeof(int), stream);
        hipMemsetAsync(h1, 0, (size_t)N * H1 * sizeof(float), stream);
        hipMemsetAsync(zz, 0, (size_t)N * H2 * sizeof(float), stream);

        k_count<<<(E + 255) / 256, 256, 0, stream>>>(col, deg, E);
        k_dinv_i<<<(N + 255) / 256, 256, 0, stream>>>(deg, dinv, N);

        k_mm<IN_DIM, H1, false><<<((long)N * H1 + 255) / 256, 256, 0, stream>>>(x, W1, dinv, h, N);
        k_scatter<H1><<<((long)E * H1 + 255) / 256, 256, 0, stream>>>(row, col, dinv, h, h1, E);
        k_finish<H1, true><<<((long)N * H1 + 255) / 256, 256, 0, stream>>>(h, dinv, b1, h1, N);

        k_mm<H1, H2, false><<<((long)N * H2 + 255) / 256, 256, 0, stream>>>(h1, W2, dinv, h2, N);
        k_scatter<H2><<<((long)E * H2 + 255) / 256, 256, 0, stream>>>(row, col, dinv, h2, zz, E);
        k_finish<H2, false><<<((long)N * H2 + 255) / 256, 256, 0, stream>>>(h2, dinv, b2, zz, N);

        dim3 dgrid((N + DT - 1) / DT, (N + DT - 1) / DT);
        k_decode<<<dgrid, 256, 0, stream>>>(zz, out, N);
    }
}